// Round 1
// baseline (333.277 us; speedup 1.0000x reference)
//
#include <hip/hip_runtime.h>

// sigma = 1e-4  ->  1/sigma = 1e4
#define INV_SIGMA 1.0e4f
#define ROUNDS 4   // chunks per thread; 256 threads * 4 = 1024 chunks/block
                   // (dropped from 8 so the fully-hoisted load set fits in
                   //  <=64 VGPRs: 4*(v4f+v4i+float)=36 live values. 64 is the
                   //  8-waves/SIMD occupancy cliff.)

typedef float v4f __attribute__((ext_vector_type(4)));
typedef int   v4i __attribute__((ext_vector_type(4)));

__device__ __forceinline__ float one_minus_prob(float d, int f) {
    // (f >= 0) ? 1 - sigmoid(-d/sigma) : 1   ==   (f >= 0) ? sigmoid(d/sigma) : 1
    float s = 1.0f / (1.0f + __expf(-d * INV_SIGMA));
    return (f >= 0) ? s : 1.0f;
}

// Chunk-transposed layout (chunk = float4 quarter-pixel), coalesced per
// instruction. R3 change: previous version INTENDED 24 loads in flight but
// VGPR_Count=32 proved the scheduler re-sank them into per-round clusters
// (~3 outstanding loads/wave -> vmcnt-wall latency-bound at 2.98 TB/s).
// Now: sched_barrier(0) pins the load cluster ahead of all compute, ROUNDS=4
// keeps the live set under the 64-VGPR occupancy cliff. 12 loads in flight
// per wave * 8 waves/SIMD = 96 outstanding requests/SIMD (4x previous).
__global__ __launch_bounds__(256) void SelfShader_9921374454199_kernel(
    const float* __restrict__ zbuf,
    const float* __restrict__ dists,
    const int*   __restrict__ p2f,
    float*       __restrict__ out,
    long long nChunks)  // 4 * N*H*W
{
    const int t = threadIdx.x;
    const long long cbase = (long long)blockIdx.x * (256 * ROUNDS) + t;

    const v4f* d4 = reinterpret_cast<const v4f*>(dists);
    const v4i* f4 = reinterpret_cast<const v4i*>(p2f);

    if (cbase + (ROUNDS - 1) * 256 < nChunks) {
        v4f   d[ROUNDS];
        v4i   f[ROUNDS];
        float z[ROUNDS];
#pragma unroll
        for (int r = 0; r < ROUNDS; ++r) {
            long long c = cbase + r * 256;
            d[r] = __builtin_nontemporal_load(d4 + c);
            f[r] = __builtin_nontemporal_load(f4 + c);
            // zbuf[pixel*16], pixel = c>>2; 4 lanes share an address (coalesces)
            z[r] = __builtin_nontemporal_load(zbuf + ((c >> 2) << 4));
        }
        // Hard scheduling fence: nothing (loads above, compute below) may be
        // reordered across this point -> all 12 loads stay issued & in flight.
        __builtin_amdgcn_sched_barrier(0);
#pragma unroll
        for (int r = 0; r < ROUNDS; ++r) {
            long long c = cbase + r * 256;
            float prod = one_minus_prob(d[r].x, f[r].x) * one_minus_prob(d[r].y, f[r].y)
                       * one_minus_prob(d[r].z, f[r].z) * one_minus_prob(d[r].w, f[r].w);
            // combine the 4 quarter-products of this pixel (lanes 4k..4k+3)
            prod *= __shfl_xor(prod, 1, 4);
            prod *= __shfl_xor(prod, 2, 4);
            float v = ((t & 3) == 3) ? (1.0f - prod) : z[r];
            __builtin_nontemporal_store(v, out + c);
        }
    } else {
        // tail path (never taken for the bench shape: 8.39M chunks / 1024 exact)
        for (int r = 0; r < ROUNDS; ++r) {
            long long c = cbase + r * 256;
            if (c >= nChunks) break;
            v4f   dd = d4[c];
            v4i   ff = f4[c];
            float zz = zbuf[(c >> 2) << 4];
            float prod = one_minus_prob(dd.x, ff.x) * one_minus_prob(dd.y, ff.y)
                       * one_minus_prob(dd.z, ff.z) * one_minus_prob(dd.w, ff.w);
            prod *= __shfl_xor(prod, 1, 4);
            prod *= __shfl_xor(prod, 2, 4);
            out[c] = ((t & 3) == 3) ? (1.0f - zz * 0.0f - prod) : zz;  // == 1-prod / zz
        }
    }
}

extern "C" void kernel_launch(void* const* d_in, const int* in_sizes, int n_in,
                              void* d_out, int out_size, void* d_ws, size_t ws_size,
                              hipStream_t stream) {
    const float* zbuf  = (const float*)d_in[0];
    const float* dists = (const float*)d_in[1];
    const int*   p2f   = (const int*)d_in[2];
    float*       out   = (float*)d_out;

    long long nChunks = (long long)in_sizes[0] / 4;  // 4 float4 chunks per pixel (K=16)
    const long long chunksPerBlock = 256LL * ROUNDS;
    int grid = (int)((nChunks + chunksPerBlock - 1) / chunksPerBlock);
    SelfShader_9921374454199_kernel<<<grid, 256, 0, stream>>>(zbuf, dists, p2f, out, nChunks);
}